// Round 3
// baseline (251.047 us; speedup 1.0000x reference)
//
#include <hip/hip_runtime.h>

#define EPSF 1e-10f

constexpr unsigned KEY15 = 0xBFC00000u;  // f2key(1.5f), bucket-aligned
constexpr int BUCK0 = 0xBFC;             // first tracked bucket (3068)
constexpr int NB2   = 4096 - BUCK0;      // 1028 tracked buckets
constexpr int NBKT  = 4096;
constexpr int NREP  = 8;                 // replica rows for flush
constexpr int LHSZ  = NB2 + 64;          // + 64 per-lane dummy slots

typedef float pf4 __attribute__((ext_vector_type(4)));
typedef int   pi4 __attribute__((ext_vector_type(4)));

// ---------- workspace layout (words) ----------
// sc: [0]=done-ticket  [8]=np(u32) [9]=qc(u32) [10]=psig(f32) [11]=plos(f32)
constexpr int SC_OFF    = 0;
constexpr int REP_OFF   = 64;                       // NREP * NB2 words
constexpr int LOW_OFF   = REP_OFF + NREP * NB2;     // fallback hist (NBKT)
constexpr int ZERO_N    = NREP * NB2 + NBKT;        // rep + low
constexpr int ZERO_TOT  = 64 + ZERO_N;              // + sc words

__device__ __forceinline__ float sigmoidf_(float x) {
    return 1.0f / (1.0f + expf(-x));
}
__device__ __forceinline__ float softplusf_(float x) {
    return fmaxf(x, 0.0f) + log1pf(expf(-fabsf(x)));
}
__device__ __forceinline__ unsigned f2key(float x) {
    unsigned b = __float_as_uint(x);
    return b ^ ((unsigned)((int)b >> 31) | 0x80000000u);
}
__device__ __forceinline__ float key2f(unsigned k) {
    unsigned b = (k & 0x80000000u) ? (k & 0x7FFFFFFFu) : ~k;
    return __uint_as_float(b);
}
__device__ __forceinline__ unsigned cload(const unsigned* p) {
    // device-coherent read (bypasses potentially stale L1/L2 copies)
    return __hip_atomic_load(p, __ATOMIC_RELAXED, __HIP_MEMORY_SCOPE_AGENT);
}

// ---------------------------------------------------------------------------
__global__ void zeroAll(unsigned* ws) {
    int stride = gridDim.x * 256;
    for (int i = blockIdx.x * 256 + threadIdx.x; i < ZERO_TOT; i += stride)
        ws[(i < 64) ? i : (REP_OFF - 64 + i)] = 0u;
}

// Single fused kernel, LAST-BLOCK pattern, FENCE-FREE.
// Round 2 lesson: per-block __threadfence() (buffer_wbl2 + buffer_inv) ran
// ~13x/us across the chip (one tile per block), continuously invalidating
// every XCD's L2 -> scan slowed 3.3x (VALUBusy 17.8->6.3%, FETCH unchanged
// since L3 absorbed the evictions). Fix: ALL cross-block communication goes
// through device-scope atomics (coherent by default, no dirty lines to
// flush): rep hist (atomicAdd, drained by the compiler's vmcnt(0) before
// s_barrier), per-block stats (4 relaxed atomicAdds replacing the bstat
// store + reduction), ticket (after an explicit bare s_waitcnt vmcnt(0)).
// The last block reads everything back with coherent sc0/sc1 atomic loads
// instead of an acquire fence.
__global__ __launch_bounds__(256) void fused(const float* __restrict__ preds,
                                             const int* __restrict__ targs, int N,
                                             unsigned* __restrict__ ws,
                                             float* __restrict__ out) {
    __shared__ int lh[LHSZ];
    __shared__ float rp[4], rs[4], rl[4], rq[4];
    __shared__ unsigned histH[NB2];
    __shared__ unsigned sa[256], sb[256];
    __shared__ int sb1;
    __shared__ unsigned sr1;
    __shared__ double rds[4], rdl[4];
    __shared__ int s_last;
    __shared__ unsigned s_np, s_k, s_flag;
    __shared__ float s_psig, s_plos;

    unsigned* sc  = ws + SC_OFF;
    unsigned* rep = ws + REP_OFF;
    unsigned* low = ws + LOW_OFF;

    for (int i = threadIdx.x; i < LHSZ; i += 256) lh[i] = 0;
    __syncthreads();

    float pc = 0.f, psig = 0.f, plos = 0.f;
    const int tid = threadIdx.x;
    const int lane = tid & 63;
    const int w = tid >> 6;
    const int dummy = NB2 + lane;            // per-lane dummy slot

    int nfull = N >> 13;                     // full 8192-element tiles
    for (int grp = blockIdx.x; grp < nfull; grp += gridDim.x) {
        size_t ebase = ((size_t)grp << 13) + ((size_t)w << 11) + ((size_t)lane << 2);
        const float* pp  = preds + ebase;        // wave tile: 2048 elements
        const float* pp2 = pp + 1024;
        const int*   tp  = targs + ebase;
        const int*   tp2 = tp + 1024;
        pf4 P[8]; pi4 T[8];
        asm volatile(
            "global_load_dwordx4 %0, %16, off\n\t"
            "global_load_dwordx4 %1, %16, off offset:1024\n\t"
            "global_load_dwordx4 %2, %16, off offset:2048\n\t"
            "global_load_dwordx4 %3, %16, off offset:3072\n\t"
            "global_load_dwordx4 %4, %17, off\n\t"
            "global_load_dwordx4 %5, %17, off offset:1024\n\t"
            "global_load_dwordx4 %6, %17, off offset:2048\n\t"
            "global_load_dwordx4 %7, %17, off offset:3072\n\t"
            "global_load_dwordx4 %8, %18, off\n\t"
            "global_load_dwordx4 %9, %18, off offset:1024\n\t"
            "global_load_dwordx4 %10, %18, off offset:2048\n\t"
            "global_load_dwordx4 %11, %18, off offset:3072\n\t"
            "global_load_dwordx4 %12, %19, off\n\t"
            "global_load_dwordx4 %13, %19, off offset:1024\n\t"
            "global_load_dwordx4 %14, %19, off offset:2048\n\t"
            "global_load_dwordx4 %15, %19, off offset:3072\n\t"
            "s_waitcnt vmcnt(0)"
            : "=&v"(P[0]), "=&v"(P[1]), "=&v"(P[2]), "=&v"(P[3]),
              "=&v"(P[4]), "=&v"(P[5]), "=&v"(P[6]), "=&v"(P[7]),
              "=&v"(T[0]), "=&v"(T[1]), "=&v"(T[2]), "=&v"(T[3]),
              "=&v"(T[4]), "=&v"(T[5]), "=&v"(T[6]), "=&v"(T[7])
            : "v"(pp), "v"(pp2), "v"(tp), "v"(tp2)
            : "memory");
#pragma unroll
        for (int g = 0; g < 8; g++) {
            pf4 pv = P[g]; pi4 tv = T[g];
#pragma unroll
            for (int j = 0; j < 4; j++) {
                float x = pv[j];
                unsigned key = f2key(x);
                int bkt = (int)(key >> 20) - BUCK0;
                bool q = (key >= KEY15) & (tv[j] == 0);
                int addr = q ? bkt : dummy;        // v_cndmask, no exec churn
                atomicAdd(&lh[addr], 1);           // unconditional ds_add
            }
            if (tv[0] | tv[1] | tv[2] | tv[3]) {   // rare positive path
#pragma unroll
                for (int j = 0; j < 4; j++)
                    if (tv[j]) {
                        float x = pv[j];
                        pc += 1.f; psig += sigmoidf_(x); plos += softplusf_(x) - x;
                    }
            }
        }
    }
    // tail elements (N % 8192), last block only
    if (blockIdx.x == gridDim.x - 1) {
        for (int i = (nfull << 13) + tid; i < N; i += 256) {
            float x = preds[i];
            if (targs[i]) { pc += 1.f; psig += sigmoidf_(x); plos += softplusf_(x) - x; }
            else {
                unsigned key = f2key(x);
                if (key >= KEY15) atomicAdd(&lh[(key >> 20) - BUCK0], 1);
            }
        }
    }
    __syncthreads();
    // flush hist (dummy slots >= NB2 ignored) + qualifying count
    float qc = 0.f;
    unsigned* my = rep + (unsigned)(blockIdx.x & (NREP - 1)) * NB2;
    for (int i = tid; i < NB2; i += 256) {
        int c = lh[i];
        if (c) { atomicAdd(&my[i], (unsigned)c); qc += (float)c; }
    }
#pragma unroll
    for (int o = 32; o > 0; o >>= 1) {
        pc   += __shfl_down(pc, o);
        psig += __shfl_down(psig, o);
        plos += __shfl_down(plos, o);
        qc   += __shfl_down(qc, o);
    }
    if ((tid & 63) == 0) { rp[w] = pc; rs[w] = psig; rl[w] = plos; rq[w] = qc; }
    __syncthreads();   // compiler drains vmcnt(0) before s_barrier -> all
                       // threads' rep atomics have completed at coherent point
    if (tid == 0) {
        unsigned npb = (unsigned)(rp[0] + rp[1] + rp[2] + rp[3] + 0.5f);
        unsigned qcb = (unsigned)(rq[0] + rq[1] + rq[2] + rq[3] + 0.5f);
        float    psb = rs[0] + rs[1] + rs[2] + rs[3];
        float    plb = rl[0] + rl[1] + rl[2] + rl[3];
        atomicAdd(&sc[8], npb);
        atomicAdd(&sc[9], qcb);
        atomicAdd((float*)sc + 10, psb);
        atomicAdd((float*)sc + 11, plb);
        asm volatile("s_waitcnt vmcnt(0)" ::: "memory");   // stats landed
        unsigned t = atomicAdd(&sc[0], 1u);                // ticket
        s_last = (t == gridDim.x - 1) ? 1 : 0;
    }
    __syncthreads();
    if (!s_last) return;                                   // all but last exit

    // ---- last block: gather global stats (coherent loads, no fence) ----
    if (tid == 0) {
        unsigned np = cload(&sc[8]);
        unsigned qtT = cload(&sc[9]);
        unsigned psb = cload(&sc[10]);
        unsigned plb = cload(&sc[11]);
        float psT = __uint_as_float(psb);
        float plT = __uint_as_float(plb);
        unsigned nn = (unsigned)N - np;
        unsigned k = (np == 0u) ? (unsigned)(0.1 * (double)nn)
                                : ((30u * np < nn) ? 30u * np : nn);
        s_np = np; s_psig = psT; s_plos = plT; s_k = k;
        s_flag = (k > qtT) ? 1u : 0u;
    }
    __syncthreads();

    // ---- last block: replica reduce into SHARED histH (coherent loads) ----
    for (int i = tid; i < NB2; i += 256) {
        unsigned s = 0;
#pragma unroll
        for (int r = 0; r < NREP; r++) s += cload(&rep[r * NB2 + i]);
        histH[i] = s;
    }

    // ---- fallback low-bucket histogram (pathological inputs only) ----
    if (s_flag) {
        for (int i = tid; i < N; i += 256) {
            if (!targs[i]) {
                unsigned key = f2key(preds[i]);
                if (key < KEY15) atomicAdd(&low[key >> 20], 1u);
            }
        }
    }
    __syncthreads();   // drains low atomics; histH visible

    // ---- last block: finalize ----
    {
        int t = tid;
        int base = t * 16;
        unsigned flag = s_flag;
        unsigned c[16]; unsigned tot = 0;
#pragma unroll
        for (int j = 0; j < 16; j++) {
            int b = base + j;
            unsigned s = (b >= BUCK0) ? histH[b - BUCK0] : (flag ? cload(&low[b]) : 0u);
            c[j] = s; tot += s;
        }
        sa[t] = tot;
        if (t == 0) { sb1 = NBKT; sr1 = 0u; }
        __syncthreads();
        unsigned k = s_k;
        unsigned* src = sa; unsigned* dst = sb;
        for (int off = 1; off < 256; off <<= 1) {
            unsigned v = src[t] + ((t + off < 256) ? src[t + off] : 0u);
            dst[t] = v;
            __syncthreads();
            unsigned* tmp = src; src = dst; dst = tmp;
        }
        if (k > 0u) {
            unsigned above = src[t] - tot;
            if (above < k && above + tot >= k) {
                unsigned cum = above;
                for (int j = 15; j >= 0; j--) {
                    unsigned cc = c[j];
                    if (cum + cc >= k) { sb1 = base + j; sr1 = k - cum; break; }
                    cum += cc;
                }
            }
        }
        __syncthreads();
        int b1 = sb1; unsigned r1 = sr1;
        double ssig = 0.0, ssp = 0.0;
#pragma unroll
        for (int j = 0; j < 16; j++) {
            int b = base + j; unsigned cc = c[j];
            if (cc == 0u) continue;
            bool full = (b > b1);
            bool part = (b == b1) && (r1 > 0u);
            if (!(full || part)) continue;
            float lo = key2f((unsigned)b << 20);
            float hi = (b == NBKT - 1) ? key2f(0xFF7FFFFFu)
                                       : key2f(((unsigned)(b + 1)) << 20);
            if (full) {
                float mid = 0.5f * (lo + hi);
                ssig += (double)cc * (double)sigmoidf_(mid);
                ssp  += (double)cc * (double)softplusf_(mid);
            } else {
                unsigned take = (r1 < cc) ? r1 : cc;
                double q = (double)take / (double)cc;
                float rpv = (float)((double)hi - 0.5 * q * ((double)hi - (double)lo));
                ssig += (double)take * (double)sigmoidf_(rpv);
                ssp  += (double)take * (double)softplusf_(rpv);
            }
        }
#pragma unroll
        for (int o = 32; o > 0; o >>= 1) {
            ssig += __shfl_down(ssig, o);
            ssp  += __shfl_down(ssp, o);
        }
        if ((t & 63) == 0) { rds[w] = ssig; rdl[w] = ssp; }
        __syncthreads();
        if (t == 0) {
            double sns = rds[0] + rds[1] + rds[2] + rds[3];
            double snl = rdl[0] + rdl[1] + rdl[2] + rdl[3];
            unsigned np = s_np;
            float psig2 = s_psig, plos2 = s_plos;
            double denom = (double)psig2 + sns + (double)np;
            double dice = 1.0 - (2.0 * (double)psig2 + (double)EPSF) / (denom + (double)EPSF);
            unsigned totsel = np + k;
            double mean = totsel ? (((double)plos2 + snl) / (double)totsel) : 0.0;
            out[0] = (float)(dice + mean);
        }
    }
}

// ---------------------------------------------------------------------------
extern "C" void kernel_launch(void* const* d_in, const int* in_sizes, int n_in,
                              void* d_out, int out_size, void* d_ws, size_t ws_size,
                              hipStream_t stream) {
    const float* preds = (const float*)d_in[0];
    const int*   targs = (const int*)d_in[1];
    float* out = (float*)d_out;
    int N = in_sizes[0];
    unsigned* ws = (unsigned*)d_ws;

    int nfull = N >> 13;
    int grid = nfull + ((N & 8191) ? 1 : 0);
    if (grid < 1) grid = 1;
    if (grid > 4096) grid = 4096;   // blocks grid-stride past

    zeroAll<<<64, 256, 0, stream>>>(ws);
    fused<<<grid, 256, 0, stream>>>(preds, targs, N, ws, out);
}

// Round 4
// 160.380 us; speedup vs baseline: 1.5653x; 1.5653x over previous
//
#include <hip/hip_runtime.h>

#define EPSF 1e-10f

constexpr unsigned KEY15 = 0xBFC00000u;  // f2key(1.5f), bucket-aligned
constexpr int BUCK0 = 0xBFC;             // first tracked bucket (3068)
constexpr int NB2   = 4096 - BUCK0;      // 1028 tracked buckets
constexpr int NBKT  = 4096;
constexpr int NREP  = 8;                 // replica rows for flush
constexpr int LHSZ  = NB2 + 64;          // + 64 per-lane dummy slots
constexpr int NGRP  = 64;                // stat/ticket spreading groups

typedef float pf4 __attribute__((ext_vector_type(4)));
typedef int   pi4 __attribute__((ext_vector_type(4)));

// ---------- workspace layout (words) ----------
// Contention-aware: done counter, 64 group-ticket lines, 64 stat lines
// (each its own 64B cache line), then rep replicas + low hist.
constexpr int DONE_OFF = 0;                          // [0] = finished-group count
constexpr int GCNT_OFF = 16;                         // 64 lines x 16 words
constexpr int STAT_OFF = GCNT_OFF + NGRP * 16;       // 64 lines x 16 words:
                                                     //  [0]=np [1]=qc [2]=psig [3]=plos
constexpr int REP_OFF  = STAT_OFF + NGRP * 16;       // NREP * NB2 words
constexpr int LOW_OFF  = REP_OFF + NREP * NB2;       // fallback hist (NBKT)
constexpr int ZERO_TOT = LOW_OFF + NBKT;             // ~14.4k words, all zeroed

__device__ __forceinline__ float sigmoidf_(float x) {
    return 1.0f / (1.0f + expf(-x));
}
__device__ __forceinline__ float softplusf_(float x) {
    return fmaxf(x, 0.0f) + log1pf(expf(-fabsf(x)));
}
__device__ __forceinline__ unsigned f2key(float x) {
    unsigned b = __float_as_uint(x);
    return b ^ ((unsigned)((int)b >> 31) | 0x80000000u);
}
__device__ __forceinline__ float key2f(unsigned k) {
    unsigned b = (k & 0x80000000u) ? (k & 0x7FFFFFFFu) : ~k;
    return __uint_as_float(b);
}
__device__ __forceinline__ unsigned cload(const unsigned* p) {
    // device-coherent read (bypasses potentially stale L1/L2 copies)
    return __hip_atomic_load(p, __ATOMIC_RELAXED, __HIP_MEMORY_SCOPE_AGENT);
}

// ---------------------------------------------------------------------------
__global__ void zeroAll(unsigned* ws) {
    int stride = gridDim.x * 256;
    for (int i = blockIdx.x * 256 + threadIdx.x; i < ZERO_TOT; i += stride)
        ws[i] = 0u;
}

// Single fused kernel, LAST-BLOCK pattern, contention-free ending.
// Round 3 post-mortem: scan was still ~46us, but ALL cross-block stats +
// ticket atomics targeted ONE 64B line -> 2048 blocks x 5 RMWs = 10240
// serialized line-RMWs ~ 110us of idle tail (VALUBusy 6%). Fix:
//  (a) stats spread over 64 lines (line = bid%64): <=128 RMWs/line, banks
//      work in parallel (~1us);
//  (b) two-level ticket: group counter (64 lines, ~32 adds each, parallel)
//      -> group-finisher bumps a single done-line (64 RMWs total);
//  (c) last block gathers the 64 stat lines with one wave of coherent loads.
// Ordering chain (validated in r3): rep/stat atomics drained by the
// compiler's vmcnt(0)-before-s_barrier and an explicit vmcnt(0); group add
// RETURNS (data dependence), done add RETURNS; last block uses coherent
// sc0/sc1 loads. No fences anywhere.
__global__ __launch_bounds__(256) void fused(const float* __restrict__ preds,
                                             const int* __restrict__ targs, int N,
                                             unsigned* __restrict__ ws,
                                             float* __restrict__ out) {
    __shared__ int lh[LHSZ];
    __shared__ float rp[4], rs[4], rl[4], rq[4];
    __shared__ unsigned histH[NB2];
    __shared__ unsigned sa[256], sb[256];
    __shared__ int sb1;
    __shared__ unsigned sr1;
    __shared__ double rds[4], rdl[4];
    __shared__ int s_last;
    __shared__ unsigned s_np, s_k, s_flag;
    __shared__ float s_psig, s_plos;

    unsigned* rep = ws + REP_OFF;
    unsigned* low = ws + LOW_OFF;

    for (int i = threadIdx.x; i < LHSZ; i += 256) lh[i] = 0;
    __syncthreads();

    float pc = 0.f, psig = 0.f, plos = 0.f;
    const int tid = threadIdx.x;
    const int lane = tid & 63;
    const int w = tid >> 6;
    const int dummy = NB2 + lane;            // per-lane dummy slot

    int nfull = N >> 13;                     // full 8192-element tiles
    for (int grp = blockIdx.x; grp < nfull; grp += gridDim.x) {
        size_t ebase = ((size_t)grp << 13) + ((size_t)w << 11) + ((size_t)lane << 2);
        const float* pp  = preds + ebase;        // wave tile: 2048 elements
        const float* pp2 = pp + 1024;
        const int*   tp  = targs + ebase;
        const int*   tp2 = tp + 1024;
        pf4 P[8]; pi4 T[8];
        asm volatile(
            "global_load_dwordx4 %0, %16, off\n\t"
            "global_load_dwordx4 %1, %16, off offset:1024\n\t"
            "global_load_dwordx4 %2, %16, off offset:2048\n\t"
            "global_load_dwordx4 %3, %16, off offset:3072\n\t"
            "global_load_dwordx4 %4, %17, off\n\t"
            "global_load_dwordx4 %5, %17, off offset:1024\n\t"
            "global_load_dwordx4 %6, %17, off offset:2048\n\t"
            "global_load_dwordx4 %7, %17, off offset:3072\n\t"
            "global_load_dwordx4 %8, %18, off\n\t"
            "global_load_dwordx4 %9, %18, off offset:1024\n\t"
            "global_load_dwordx4 %10, %18, off offset:2048\n\t"
            "global_load_dwordx4 %11, %18, off offset:3072\n\t"
            "global_load_dwordx4 %12, %19, off\n\t"
            "global_load_dwordx4 %13, %19, off offset:1024\n\t"
            "global_load_dwordx4 %14, %19, off offset:2048\n\t"
            "global_load_dwordx4 %15, %19, off offset:3072\n\t"
            "s_waitcnt vmcnt(0)"
            : "=&v"(P[0]), "=&v"(P[1]), "=&v"(P[2]), "=&v"(P[3]),
              "=&v"(P[4]), "=&v"(P[5]), "=&v"(P[6]), "=&v"(P[7]),
              "=&v"(T[0]), "=&v"(T[1]), "=&v"(T[2]), "=&v"(T[3]),
              "=&v"(T[4]), "=&v"(T[5]), "=&v"(T[6]), "=&v"(T[7])
            : "v"(pp), "v"(pp2), "v"(tp), "v"(tp2)
            : "memory");
#pragma unroll
        for (int g = 0; g < 8; g++) {
            pf4 pv = P[g]; pi4 tv = T[g];
#pragma unroll
            for (int j = 0; j < 4; j++) {
                float x = pv[j];
                unsigned key = f2key(x);
                int bkt = (int)(key >> 20) - BUCK0;
                bool q = (key >= KEY15) & (tv[j] == 0);
                int addr = q ? bkt : dummy;        // v_cndmask, no exec churn
                atomicAdd(&lh[addr], 1);           // unconditional ds_add
            }
            if (tv[0] | tv[1] | tv[2] | tv[3]) {   // rare positive path
#pragma unroll
                for (int j = 0; j < 4; j++)
                    if (tv[j]) {
                        float x = pv[j];
                        pc += 1.f; psig += sigmoidf_(x); plos += softplusf_(x) - x;
                    }
            }
        }
    }
    // tail elements (N % 8192), last block only
    if (blockIdx.x == gridDim.x - 1) {
        for (int i = (nfull << 13) + tid; i < N; i += 256) {
            float x = preds[i];
            if (targs[i]) { pc += 1.f; psig += sigmoidf_(x); plos += softplusf_(x) - x; }
            else {
                unsigned key = f2key(x);
                if (key >= KEY15) atomicAdd(&lh[(key >> 20) - BUCK0], 1);
            }
        }
    }
    __syncthreads();
    // flush hist (dummy slots >= NB2 ignored) + qualifying count
    float qc = 0.f;
    unsigned* my = rep + (unsigned)(blockIdx.x & (NREP - 1)) * NB2;
    for (int i = tid; i < NB2; i += 256) {
        int c = lh[i];
        if (c) { atomicAdd(&my[i], (unsigned)c); qc += (float)c; }
    }
#pragma unroll
    for (int o = 32; o > 0; o >>= 1) {
        pc   += __shfl_down(pc, o);
        psig += __shfl_down(psig, o);
        plos += __shfl_down(plos, o);
        qc   += __shfl_down(qc, o);
    }
    if ((tid & 63) == 0) { rp[w] = pc; rs[w] = psig; rl[w] = plos; rq[w] = qc; }
    __syncthreads();   // compiler drains vmcnt(0) before s_barrier -> all
                       // threads' rep atomics have reached the coherent point
    if (tid == 0) {
        unsigned npb = (unsigned)(rp[0] + rp[1] + rp[2] + rp[3] + 0.5f);
        unsigned qcb = (unsigned)(rq[0] + rq[1] + rq[2] + rq[3] + 0.5f);
        float    psb = rs[0] + rs[1] + rs[2] + rs[3];
        float    plb = rl[0] + rl[1] + rl[2] + rl[3];
        unsigned ng  = (gridDim.x < (unsigned)NGRP) ? gridDim.x : (unsigned)NGRP;
        unsigned g   = blockIdx.x % ng;
        unsigned* line = ws + STAT_OFF + g * 16;
        atomicAdd(&line[0], npb);
        atomicAdd(&line[1], qcb);
        atomicAdd((float*)&line[2], psb);
        atomicAdd((float*)&line[3], plb);
        asm volatile("s_waitcnt vmcnt(0)" ::: "memory");   // stats landed
        unsigned expect = (gridDim.x - 1u - g) / ng + 1u;  // blocks in group g
        unsigned t = atomicAdd(&ws[GCNT_OFF + g * 16], 1u);
        int lastflag = 0;
        if (t == expect - 1u) {                            // group finisher
            unsigned d = atomicAdd(&ws[DONE_OFF], 1u);
            lastflag = (d == ng - 1u);                     // global last
        }
        s_last = lastflag;
    }
    __syncthreads();
    if (!s_last) return;                                   // all but last exit

    // ---- last block: gather spread stats (one wave, coherent loads) ----
    if (tid < 64) {
        const unsigned* line = ws + STAT_OFF + tid * 16;
        unsigned np_ = cload(&line[0]);
        unsigned qc_ = cload(&line[1]);
        float    ps_ = __uint_as_float(cload(&line[2]));
        float    pl_ = __uint_as_float(cload(&line[3]));
#pragma unroll
        for (int o = 32; o > 0; o >>= 1) {
            np_ += __shfl_down(np_, o);
            qc_ += __shfl_down(qc_, o);
            ps_ += __shfl_down(ps_, o);
            pl_ += __shfl_down(pl_, o);
        }
        if (tid == 0) {
            unsigned np = np_;
            unsigned nn = (unsigned)N - np;
            unsigned k = (np == 0u) ? (unsigned)(0.1 * (double)nn)
                                    : ((30u * np < nn) ? 30u * np : nn);
            s_np = np; s_psig = ps_; s_plos = pl_; s_k = k;
            s_flag = (k > qc_) ? 1u : 0u;
        }
    }
    __syncthreads();

    // ---- last block: replica reduce into SHARED histH (coherent loads) ----
    for (int i = tid; i < NB2; i += 256) {
        unsigned s = 0;
#pragma unroll
        for (int r = 0; r < NREP; r++) s += cload(&rep[r * NB2 + i]);
        histH[i] = s;
    }

    // ---- fallback low-bucket histogram (pathological inputs only) ----
    if (s_flag) {
        for (int i = tid; i < N; i += 256) {
            if (!targs[i]) {
                unsigned key = f2key(preds[i]);
                if (key < KEY15) atomicAdd(&low[key >> 20], 1u);
            }
        }
    }
    __syncthreads();   // drains low atomics; histH visible

    // ---- last block: finalize ----
    {
        int t = tid;
        int base = t * 16;
        unsigned flag = s_flag;
        unsigned c[16]; unsigned tot = 0;
#pragma unroll
        for (int j = 0; j < 16; j++) {
            int b = base + j;
            unsigned s = (b >= BUCK0) ? histH[b - BUCK0] : (flag ? cload(&low[b]) : 0u);
            c[j] = s; tot += s;
        }
        sa[t] = tot;
        if (t == 0) { sb1 = NBKT; sr1 = 0u; }
        __syncthreads();
        unsigned k = s_k;
        unsigned* src = sa; unsigned* dst = sb;
        for (int off = 1; off < 256; off <<= 1) {
            unsigned v = src[t] + ((t + off < 256) ? src[t + off] : 0u);
            dst[t] = v;
            __syncthreads();
            unsigned* tmp = src; src = dst; dst = tmp;
        }
        if (k > 0u) {
            unsigned above = src[t] - tot;
            if (above < k && above + tot >= k) {
                unsigned cum = above;
                for (int j = 15; j >= 0; j--) {
                    unsigned cc = c[j];
                    if (cum + cc >= k) { sb1 = base + j; sr1 = k - cum; break; }
                    cum += cc;
                }
            }
        }
        __syncthreads();
        int b1 = sb1; unsigned r1 = sr1;
        double ssig = 0.0, ssp = 0.0;
#pragma unroll
        for (int j = 0; j < 16; j++) {
            int b = base + j; unsigned cc = c[j];
            if (cc == 0u) continue;
            bool full = (b > b1);
            bool part = (b == b1) && (r1 > 0u);
            if (!(full || part)) continue;
            float lo = key2f((unsigned)b << 20);
            float hi = (b == NBKT - 1) ? key2f(0xFF7FFFFFu)
                                       : key2f(((unsigned)(b + 1)) << 20);
            if (full) {
                float mid = 0.5f * (lo + hi);
                ssig += (double)cc * (double)sigmoidf_(mid);
                ssp  += (double)cc * (double)softplusf_(mid);
            } else {
                unsigned take = (r1 < cc) ? r1 : cc;
                double q = (double)take / (double)cc;
                float rpv = (float)((double)hi - 0.5 * q * ((double)hi - (double)lo));
                ssig += (double)take * (double)sigmoidf_(rpv);
                ssp  += (double)take * (double)softplusf_(rpv);
            }
        }
#pragma unroll
        for (int o = 32; o > 0; o >>= 1) {
            ssig += __shfl_down(ssig, o);
            ssp  += __shfl_down(ssp, o);
        }
        if ((t & 63) == 0) { rds[w] = ssig; rdl[w] = ssp; }
        __syncthreads();
        if (t == 0) {
            double sns = rds[0] + rds[1] + rds[2] + rds[3];
            double snl = rdl[0] + rdl[1] + rdl[2] + rdl[3];
            unsigned np = s_np;
            float psig2 = s_psig, plos2 = s_plos;
            double denom = (double)psig2 + sns + (double)np;
            double dice = 1.0 - (2.0 * (double)psig2 + (double)EPSF) / (denom + (double)EPSF);
            unsigned totsel = np + k;
            double mean = totsel ? (((double)plos2 + snl) / (double)totsel) : 0.0;
            out[0] = (float)(dice + mean);
        }
    }
}

// ---------------------------------------------------------------------------
extern "C" void kernel_launch(void* const* d_in, const int* in_sizes, int n_in,
                              void* d_out, int out_size, void* d_ws, size_t ws_size,
                              hipStream_t stream) {
    const float* preds = (const float*)d_in[0];
    const int*   targs = (const int*)d_in[1];
    float* out = (float*)d_out;
    int N = in_sizes[0];
    unsigned* ws = (unsigned*)d_ws;

    int nfull = N >> 13;
    int grid = nfull + ((N & 8191) ? 1 : 0);
    if (grid < 1) grid = 1;
    if (grid > 4096) grid = 4096;   // blocks grid-stride past

    zeroAll<<<64, 256, 0, stream>>>(ws);
    fused<<<grid, 256, 0, stream>>>(preds, targs, N, ws, out);
}